// Round 1
// baseline (6595.145 us; speedup 1.0000x reference)
//
#include <hip/hip_runtime.h>
#include <math.h>

#define NN 100000
#define NE 3200000
#define XD 2000
#define HID 128
#define NC 20

#define FEAT_OFF  ((size_t)NN * NC)                    // 2,000,000
#define OFEAT_OFF (FEAT_OFF + (size_t)NN * HID)        // 14,800,000

// ---------------------------------------------------------------------------
// Detect whether edge_index is int64 (odd 32-bit words all zero) or int32.
// Writes 1 to *flag for int64, 0 for int32. Deterministic per launch.
// ---------------------------------------------------------------------------
__global__ void detect_idx_kernel(const unsigned* __restrict__ ei, int* __restrict__ flag) {
    if (threadIdx.x == 0) {
        bool hz = true;
        for (int i = 0; i < 16; ++i) hz = hz && (ei[2 * i + 1] == 0u);
        *flag = hz ? 1 : 0;
    }
}

// ---------------------------------------------------------------------------
// Normalize columns of Wn [HID][NC] -> WnHat
// ---------------------------------------------------------------------------
__global__ void wn_norm_kernel(const float* __restrict__ Wn, float* __restrict__ WnHat) {
    int c = threadIdx.x;
    if (c >= NC) return;
    float s = 0.f;
    for (int k = 0; k < HID; ++k) { float w = Wn[k * NC + c]; s = fmaf(w, w, s); }
    float inv = 1.f / fmaxf(sqrtf(s), 1e-12f);
    for (int k = 0; k < HID; ++k) WnHat[k * NC + c] = Wn[k * NC + c] * inv;
}

// ---------------------------------------------------------------------------
// GEMM1: feat = x @ W1 + b1.   [NN x XD] @ [XD x HID]
// Block = 256 threads computes a 64x128 tile. BK=16. fp32 vector FMA.
// ---------------------------------------------------------------------------
__global__ __launch_bounds__(256) void gemm1_kernel(const float* __restrict__ x,
                                                    const float* __restrict__ W1,
                                                    const float* __restrict__ b1,
                                                    float* __restrict__ feat) {
    __shared__ float sX[16][64];    // transposed x tile [k][row]
    __shared__ float sW[16][128];   // W1 tile [k][col]

    const int t = threadIdx.x;
    const int ty = t >> 4;          // 0..15 : rows ty*4 .. ty*4+3
    const int tx = t & 15;          // cols tx*8 .. tx*8+7
    const int row0 = blockIdx.x * 64;

    const int lrow = t & 63;        // x-loader: row within tile
    const int lkc  = t >> 6;        // x-loader: k-chunk (0..3), 4 floats each
    const int grow = row0 + lrow;

    const float4 bb0 = *(const float4*)(b1 + tx * 8);
    const float4 bb1 = *(const float4*)(b1 + tx * 8 + 4);

    float acc[4][8];
#pragma unroll
    for (int r = 0; r < 4; ++r) {
        acc[r][0] = bb0.x; acc[r][1] = bb0.y; acc[r][2] = bb0.z; acc[r][3] = bb0.w;
        acc[r][4] = bb1.x; acc[r][5] = bb1.y; acc[r][6] = bb1.z; acc[r][7] = bb1.w;
    }

    const float* xrow = x + (size_t)grow * XD;

    for (int k0 = 0; k0 < XD; k0 += 16) {
        float4 xv = make_float4(0.f, 0.f, 0.f, 0.f);
        if (grow < NN) xv = *(const float4*)(xrow + k0 + lkc * 4);
        const float4 wv0 = *(const float4*)(W1 + (size_t)(k0 + ty) * HID + tx * 8);
        const float4 wv1 = *(const float4*)(W1 + (size_t)(k0 + ty) * HID + tx * 8 + 4);

        __syncthreads();
        sX[lkc * 4 + 0][lrow] = xv.x;
        sX[lkc * 4 + 1][lrow] = xv.y;
        sX[lkc * 4 + 2][lrow] = xv.z;
        sX[lkc * 4 + 3][lrow] = xv.w;
        *(float4*)&sW[ty][tx * 8]     = wv0;
        *(float4*)&sW[ty][tx * 8 + 4] = wv1;
        __syncthreads();

#pragma unroll
        for (int kk = 0; kk < 16; ++kk) {
            const float4 a  = *(const float4*)&sX[kk][ty * 4];
            const float4 w0 = *(const float4*)&sW[kk][tx * 8];
            const float4 w1 = *(const float4*)&sW[kk][tx * 8 + 4];
            const float ar[4] = {a.x, a.y, a.z, a.w};
#pragma unroll
            for (int r = 0; r < 4; ++r) {
                acc[r][0] = fmaf(ar[r], w0.x, acc[r][0]);
                acc[r][1] = fmaf(ar[r], w0.y, acc[r][1]);
                acc[r][2] = fmaf(ar[r], w0.z, acc[r][2]);
                acc[r][3] = fmaf(ar[r], w0.w, acc[r][3]);
                acc[r][4] = fmaf(ar[r], w1.x, acc[r][4]);
                acc[r][5] = fmaf(ar[r], w1.y, acc[r][5]);
                acc[r][6] = fmaf(ar[r], w1.z, acc[r][6]);
                acc[r][7] = fmaf(ar[r], w1.w, acc[r][7]);
            }
        }
    }

#pragma unroll
    for (int r = 0; r < 4; ++r) {
        const int row = row0 + ty * 4 + r;
        if (row < NN) {
            float4 o0, o1;
            o0.x = acc[r][0]; o0.y = acc[r][1]; o0.z = acc[r][2]; o0.w = acc[r][3];
            o1.x = acc[r][4]; o1.y = acc[r][5]; o1.z = acc[r][6]; o1.w = acc[r][7];
            *(float4*)(feat + (size_t)row * HID + tx * 8)     = o0;
            *(float4*)(feat + (size_t)row * HID + tx * 8 + 4) = o1;
        }
    }
}

// ---------------------------------------------------------------------------
// Scatter: msg[dst] += relu(feat[src]); deg[dst] += 1.   32 lanes per edge.
// ---------------------------------------------------------------------------
__global__ __launch_bounds__(256) void scatter_kernel(const unsigned* __restrict__ ei,
                                                      const int* __restrict__ flag,
                                                      const float* __restrict__ feat,
                                                      float* __restrict__ msg,
                                                      float* __restrict__ deg) {
    const long long g = (long long)blockIdx.x * blockDim.x + threadIdx.x;
    const long long e = g >> 5;
    const int lane = (int)(g & 31);
    if (e >= NE) return;

    const int f = *flag;
    const size_t si = f ? (size_t)(2 * e)               : (size_t)e;
    const size_t di = f ? (size_t)(2 * ((long long)NE + e)) : (size_t)((long long)NE + e);
    const unsigned src = ei[si];
    const unsigned dst = ei[di];

    float4 v = *(const float4*)(feat + (size_t)src * HID + lane * 4);
    v.x = fmaxf(v.x, 0.f); v.y = fmaxf(v.y, 0.f);
    v.z = fmaxf(v.z, 0.f); v.w = fmaxf(v.w, 0.f);

    float* m = msg + (size_t)dst * HID + lane * 4;
    atomicAdd(m + 0, v.x);
    atomicAdd(m + 1, v.y);
    atomicAdd(m + 2, v.z);
    atomicAdd(m + 3, v.w);
    if (lane == 0) atomicAdd(deg + dst, 1.0f);
}

// ---------------------------------------------------------------------------
// Combine: out_feat = (msg/deg) @ Wl + bl + relu(feat) @ Wr    (in-place over msg)
//          out      = 10 * rownorm(out_feat) @ WnHat
// Weights cached in LDS (fp32). 16 nodes per chunk, grid-stride over chunks.
// ---------------------------------------------------------------------------
#define NT 16
__global__ __launch_bounds__(256) void combine_kernel(const float* __restrict__ Wl,
                                                      const float* __restrict__ bl,
                                                      const float* __restrict__ Wr,
                                                      const float* __restrict__ WnHat,
                                                      const float* __restrict__ deg,
                                                      const float* __restrict__ feat,
                                                      float* __restrict__ out,
                                                      float* __restrict__ ofeat) {
    __shared__ float sWl[HID][HID];   // 64 KB
    __shared__ float sWr[HID][HID];   // 64 KB
    __shared__ float sWn[HID][NC];    // 10 KB
    __shared__ float sBl[HID];
    __shared__ float sA[NT][HID];     // agg rows, later reused for out_feat rows
    __shared__ float sH[NT][HID];     // relu(feat) rows
    __shared__ float sScale[NT];

    const int t = threadIdx.x;

    for (int i = t; i < HID * HID / 4; i += 256) {
        ((float4*)sWl)[i] = ((const float4*)Wl)[i];
        ((float4*)sWr)[i] = ((const float4*)Wr)[i];
    }
    for (int i = t; i < HID * NC; i += 256) ((float*)sWn)[i] = WnHat[i];
    if (t < HID) sBl[t] = bl[t];

    const int cg = t & 31;      // col group: cols cg*4 .. cg*4+3
    const int ng = t >> 5;      // node group: nodes ng*2, ng*2+1
    const int c0 = cg * 4;
    const int n0 = ng * 2, n1 = ng * 2 + 1;
    const int nchunks = NN / NT;   // 6250, exact

    for (int ch = blockIdx.x; ch < nchunks; ch += gridDim.x) {
        const int base = ch * NT;
        __syncthreads();   // protect sA/sH reuse across iterations (covers weight loads on iter 0)

        // load agg rows (msg/deg) and relu(feat) rows
        for (int i = t; i < NT * (HID / 4); i += 256) {
            const int n = i >> 5;
            const int k4 = (i & 31) * 4;
            const int node = base + n;
            const float d = fmaxf(deg[node], 1.0f);
            float4 mv = *(const float4*)(ofeat + (size_t)node * HID + k4);
            sA[n][k4 + 0] = mv.x / d; sA[n][k4 + 1] = mv.y / d;
            sA[n][k4 + 2] = mv.z / d; sA[n][k4 + 3] = mv.w / d;
            float4 fv = *(const float4*)(feat + (size_t)node * HID + k4);
            sH[n][k4 + 0] = fmaxf(fv.x, 0.f); sH[n][k4 + 1] = fmaxf(fv.y, 0.f);
            sH[n][k4 + 2] = fmaxf(fv.z, 0.f); sH[n][k4 + 3] = fmaxf(fv.w, 0.f);
        }
        __syncthreads();

        // out_feat = agg @ Wl + bl + h @ Wr  (2 nodes x 4 cols per thread)
        float4 acc0, acc1;
        acc0.x = sBl[c0]; acc0.y = sBl[c0 + 1]; acc0.z = sBl[c0 + 2]; acc0.w = sBl[c0 + 3];
        acc1 = acc0;
#pragma unroll 8
        for (int k = 0; k < HID; ++k) {
            const float4 wl = *(const float4*)&sWl[k][c0];
            const float4 wr = *(const float4*)&sWr[k][c0];
            const float a0 = sA[n0][k], a1 = sA[n1][k];
            const float h0 = sH[n0][k], h1 = sH[n1][k];
            acc0.x = fmaf(a0, wl.x, acc0.x); acc0.y = fmaf(a0, wl.y, acc0.y);
            acc0.z = fmaf(a0, wl.z, acc0.z); acc0.w = fmaf(a0, wl.w, acc0.w);
            acc0.x = fmaf(h0, wr.x, acc0.x); acc0.y = fmaf(h0, wr.y, acc0.y);
            acc0.z = fmaf(h0, wr.z, acc0.z); acc0.w = fmaf(h0, wr.w, acc0.w);
            acc1.x = fmaf(a1, wl.x, acc1.x); acc1.y = fmaf(a1, wl.y, acc1.y);
            acc1.z = fmaf(a1, wl.z, acc1.z); acc1.w = fmaf(a1, wl.w, acc1.w);
            acc1.x = fmaf(h1, wr.x, acc1.x); acc1.y = fmaf(h1, wr.y, acc1.y);
            acc1.z = fmaf(h1, wr.z, acc1.z); acc1.w = fmaf(h1, wr.w, acc1.w);
        }
        __syncthreads();   // everyone done reading sA/sH

        // write out_feat to global and stash rows into sA for normalization
        *(float4*)&sA[n0][c0] = acc0;
        *(float4*)&sA[n1][c0] = acc1;
        *(float4*)(ofeat + (size_t)(base + n0) * HID + c0) = acc0;
        *(float4*)(ofeat + (size_t)(base + n1) * HID + c0) = acc1;
        __syncthreads();

        // row norms -> scale = 10 / max(norm, 1e-12)
        if (t < NT) {
            float s = 0.f;
            for (int k = 0; k < HID; ++k) { const float v = sA[t][k]; s = fmaf(v, v, s); }
            sScale[t] = 10.f / fmaxf(sqrtf(s), 1e-12f);
        }
        __syncthreads();

        // out = scale * (out_feat @ WnHat)
        for (int i = t; i < NT * NC; i += 256) {
            const int n = i / NC;
            const int c = i % NC;
            float s = 0.f;
            for (int k = 0; k < HID; ++k) s = fmaf(sA[n][k], sWn[k][c], s);
            out[(size_t)(base + n) * NC + c] = sScale[n] * s;
        }
    }
}

// ---------------------------------------------------------------------------
extern "C" void kernel_launch(void* const* d_in, const int* in_sizes, int n_in,
                              void* d_out, int out_size, void* d_ws, size_t ws_size,
                              hipStream_t stream) {
    const float*    x  = (const float*)d_in[0];
    const unsigned* ei = (const unsigned*)d_in[1];
    const float*    W1 = (const float*)d_in[2];
    const float*    b1 = (const float*)d_in[3];
    const float*    Wl = (const float*)d_in[4];
    const float*    bl = (const float*)d_in[5];
    const float*    Wr = (const float*)d_in[6];
    const float*    Wn = (const float*)d_in[7];

    float* out   = (float*)d_out;
    float* feat  = out + FEAT_OFF;
    float* ofeat = out + OFEAT_OFF;   // doubles as msg accumulator

    int*   flag  = (int*)d_ws;
    float* WnHat = (float*)((char*)d_ws + 256);
    float* deg   = (float*)((char*)d_ws + 16384);

    detect_idx_kernel<<<1, 64, 0, stream>>>(ei, flag);
    wn_norm_kernel<<<1, 32, 0, stream>>>(Wn, WnHat);
    hipMemsetAsync(ofeat, 0, (size_t)NN * HID * sizeof(float), stream);
    hipMemsetAsync(deg, 0, (size_t)NN * sizeof(float), stream);

    gemm1_kernel<<<(NN + 63) / 64, 256, 0, stream>>>(x, W1, b1, feat);
    scatter_kernel<<<(int)(((long long)NE * 32) / 256), 256, 0, stream>>>(ei, flag, feat, ofeat, deg);
    combine_kernel<<<512, 256, 0, stream>>>(Wl, bl, Wr, WnHat, deg, feat, out, ofeat);
}

// Round 2
// 1650.921 us; speedup vs baseline: 3.9948x; 3.9948x over previous
//
#include <hip/hip_runtime.h>
#include <math.h>

#define NN 100000
#define NE 3200000
#define XD 2000
#define HID 128
#define NC 20

#define FEAT_OFF  ((size_t)NN * NC)                    // 2,000,000
#define OFEAT_OFF (FEAT_OFF + (size_t)NN * HID)        // 14,800,000

// ws layout (bytes)
#define WS_FLAG    0
#define WS_WNHAT   256
#define WS_CNT     16384                // int[NN]  (also float deg in fallback)
#define WS_ROWS    417792               // int[NN+1]
#define WS_CURSOR  819200               // int[NN]
#define WS_BSUM    1220608              // int[128]
#define WS_CSR     1245184              // int[NE]
#define WS_NEEDED  (WS_CSR + (size_t)NE * 4 + 1024)

#define NB_SCAN 98                      // ceil(NN/1024)

// ---------------------------------------------------------------------------
// Detect whether edge_index is int64 (odd 32-bit words all zero) or int32.
// ---------------------------------------------------------------------------
__global__ void detect_idx_kernel(const unsigned* __restrict__ ei, int* __restrict__ flag) {
    if (threadIdx.x == 0) {
        bool hz = true;
        for (int i = 0; i < 16; ++i) hz = hz && (ei[2 * i + 1] == 0u);
        *flag = hz ? 1 : 0;
    }
}

// ---------------------------------------------------------------------------
// Normalize columns of Wn [HID][NC] -> WnHat
// ---------------------------------------------------------------------------
__global__ void wn_norm_kernel(const float* __restrict__ Wn, float* __restrict__ WnHat) {
    int c = threadIdx.x;
    if (c >= NC) return;
    float s = 0.f;
    for (int k = 0; k < HID; ++k) { float w = Wn[k * NC + c]; s = fmaf(w, w, s); }
    float inv = 1.f / fmaxf(sqrtf(s), 1e-12f);
    for (int k = 0; k < HID; ++k) WnHat[k * NC + c] = Wn[k * NC + c] * inv;
}

// ---------------------------------------------------------------------------
// GEMM1: feat = x @ W1 + b1.   [NN x XD] @ [XD x HID]
// ---------------------------------------------------------------------------
__global__ __launch_bounds__(256) void gemm1_kernel(const float* __restrict__ x,
                                                    const float* __restrict__ W1,
                                                    const float* __restrict__ b1,
                                                    float* __restrict__ feat) {
    __shared__ float sX[16][64];
    __shared__ float sW[16][128];

    const int t = threadIdx.x;
    const int ty = t >> 4;
    const int tx = t & 15;
    const int row0 = blockIdx.x * 64;

    const int lrow = t & 63;
    const int lkc  = t >> 6;
    const int grow = row0 + lrow;

    const float4 bb0 = *(const float4*)(b1 + tx * 8);
    const float4 bb1 = *(const float4*)(b1 + tx * 8 + 4);

    float acc[4][8];
#pragma unroll
    for (int r = 0; r < 4; ++r) {
        acc[r][0] = bb0.x; acc[r][1] = bb0.y; acc[r][2] = bb0.z; acc[r][3] = bb0.w;
        acc[r][4] = bb1.x; acc[r][5] = bb1.y; acc[r][6] = bb1.z; acc[r][7] = bb1.w;
    }

    const float* xrow = x + (size_t)grow * XD;

    for (int k0 = 0; k0 < XD; k0 += 16) {
        float4 xv = make_float4(0.f, 0.f, 0.f, 0.f);
        if (grow < NN) xv = *(const float4*)(xrow + k0 + lkc * 4);
        const float4 wv0 = *(const float4*)(W1 + (size_t)(k0 + ty) * HID + tx * 8);
        const float4 wv1 = *(const float4*)(W1 + (size_t)(k0 + ty) * HID + tx * 8 + 4);

        __syncthreads();
        sX[lkc * 4 + 0][lrow] = xv.x;
        sX[lkc * 4 + 1][lrow] = xv.y;
        sX[lkc * 4 + 2][lrow] = xv.z;
        sX[lkc * 4 + 3][lrow] = xv.w;
        *(float4*)&sW[ty][tx * 8]     = wv0;
        *(float4*)&sW[ty][tx * 8 + 4] = wv1;
        __syncthreads();

#pragma unroll
        for (int kk = 0; kk < 16; ++kk) {
            const float4 a  = *(const float4*)&sX[kk][ty * 4];
            const float4 w0 = *(const float4*)&sW[kk][tx * 8];
            const float4 w1 = *(const float4*)&sW[kk][tx * 8 + 4];
            const float ar[4] = {a.x, a.y, a.z, a.w};
#pragma unroll
            for (int r = 0; r < 4; ++r) {
                acc[r][0] = fmaf(ar[r], w0.x, acc[r][0]);
                acc[r][1] = fmaf(ar[r], w0.y, acc[r][1]);
                acc[r][2] = fmaf(ar[r], w0.z, acc[r][2]);
                acc[r][3] = fmaf(ar[r], w0.w, acc[r][3]);
                acc[r][4] = fmaf(ar[r], w1.x, acc[r][4]);
                acc[r][5] = fmaf(ar[r], w1.y, acc[r][5]);
                acc[r][6] = fmaf(ar[r], w1.z, acc[r][6]);
                acc[r][7] = fmaf(ar[r], w1.w, acc[r][7]);
            }
        }
    }

#pragma unroll
    for (int r = 0; r < 4; ++r) {
        const int row = row0 + ty * 4 + r;
        if (row < NN) {
            float4 o0, o1;
            o0.x = acc[r][0]; o0.y = acc[r][1]; o0.z = acc[r][2]; o0.w = acc[r][3];
            o1.x = acc[r][4]; o1.y = acc[r][5]; o1.z = acc[r][6]; o1.w = acc[r][7];
            *(float4*)(feat + (size_t)row * HID + tx * 8)     = o0;
            *(float4*)(feat + (size_t)row * HID + tx * 8 + 4) = o1;
        }
    }
}

// ---------------------------------------------------------------------------
// CSR build: histogram, 3-step scan, fill
// ---------------------------------------------------------------------------
__global__ __launch_bounds__(256) void hist_kernel(const unsigned* __restrict__ ei,
                                                   const int* __restrict__ flag,
                                                   int* __restrict__ cnt) {
    const long long e = (long long)blockIdx.x * blockDim.x + threadIdx.x;
    if (e >= NE) return;
    const int f = *flag;
    const size_t di = f ? (size_t)(2 * ((long long)NE + e)) : (size_t)((long long)NE + e);
    atomicAdd(&cnt[ei[di]], 1);
}

__global__ __launch_bounds__(1024) void scan1_kernel(const int* __restrict__ cnt,
                                                     int* __restrict__ rs,
                                                     int* __restrict__ bsum) {
    __shared__ int sd[1024];
    const int t = threadIdx.x;
    const int i = blockIdx.x * 1024 + t;
    const int v = (i < NN) ? cnt[i] : 0;
    sd[t] = v;
    __syncthreads();
    for (int off = 1; off < 1024; off <<= 1) {
        const int u = (t >= off) ? sd[t - off] : 0;
        __syncthreads();
        sd[t] += u;
        __syncthreads();
    }
    if (i < NN) rs[i] = sd[t] - v;      // block-local exclusive
    if (t == 1023) bsum[blockIdx.x] = sd[1023];
}

__global__ void scan2_kernel(int* __restrict__ bsum) {
    if (threadIdx.x == 0) {
        int run = 0;
        for (int b = 0; b < NB_SCAN; ++b) { const int x = bsum[b]; bsum[b] = run; run += x; }
    }
}

__global__ __launch_bounds__(1024) void scan3_kernel(int* __restrict__ rs,
                                                     int* __restrict__ cursor,
                                                     const int* __restrict__ bsum) {
    const int i = blockIdx.x * 1024 + threadIdx.x;
    if (i < NN) {
        const int v = rs[i] + bsum[i >> 10];
        rs[i] = v;
        cursor[i] = v;
    }
    if (i == 0) rs[NN] = NE;
}

__global__ __launch_bounds__(256) void fill_kernel(const unsigned* __restrict__ ei,
                                                   const int* __restrict__ flag,
                                                   int* __restrict__ cursor,
                                                   int* __restrict__ csr) {
    const long long e = (long long)blockIdx.x * blockDim.x + threadIdx.x;
    if (e >= NE) return;
    const int f = *flag;
    const size_t si = f ? (size_t)(2 * e)                    : (size_t)e;
    const size_t di = f ? (size_t)(2 * ((long long)NE + e))  : (size_t)((long long)NE + e);
    const unsigned src = ei[si];
    const unsigned dst = ei[di];
    const int pos = atomicAdd(&cursor[dst], 1);
    csr[pos] = (int)src;
}

// ---------------------------------------------------------------------------
// Gather (pull): agg[n] = mean_{j in N(n)} relu(feat[src_j]).  One wave/node.
// ---------------------------------------------------------------------------
__global__ __launch_bounds__(256) void gather_kernel(const int* __restrict__ rs,
                                                     const int* __restrict__ csr,
                                                     const float* __restrict__ feat,
                                                     float* __restrict__ agg) {
    const int lane = threadIdx.x & 63;
    const int gw = (blockIdx.x * 256 + threadIdx.x) >> 6;
    const int nw = gridDim.x * 4;
    const int o = lane * 2;

    for (int n = gw; n < NN; n += nw) {
        const int s = rs[n];
        const int e2 = rs[n + 1];
        float ax = 0.f, ay = 0.f;
        int j = s;
        for (; j + 4 <= e2; j += 4) {
            const int s0 = csr[j], s1 = csr[j + 1], s2 = csr[j + 2], s3 = csr[j + 3];
            const float2 v0 = *(const float2*)(feat + (size_t)s0 * HID + o);
            const float2 v1 = *(const float2*)(feat + (size_t)s1 * HID + o);
            const float2 v2 = *(const float2*)(feat + (size_t)s2 * HID + o);
            const float2 v3 = *(const float2*)(feat + (size_t)s3 * HID + o);
            ax += fmaxf(v0.x, 0.f) + fmaxf(v1.x, 0.f) + fmaxf(v2.x, 0.f) + fmaxf(v3.x, 0.f);
            ay += fmaxf(v0.y, 0.f) + fmaxf(v1.y, 0.f) + fmaxf(v2.y, 0.f) + fmaxf(v3.y, 0.f);
        }
        for (; j < e2; ++j) {
            const float2 v = *(const float2*)(feat + (size_t)csr[j] * HID + o);
            ax += fmaxf(v.x, 0.f);
            ay += fmaxf(v.y, 0.f);
        }
        const float d = fmaxf((float)(e2 - s), 1.f);
        *(float2*)(agg + (size_t)n * HID + o) = make_float2(ax / d, ay / d);
    }
}

// ---------------------------------------------------------------------------
// Fallback scatter path (used only if ws too small for CSR)
// ---------------------------------------------------------------------------
__global__ __launch_bounds__(256) void scatter_kernel(const unsigned* __restrict__ ei,
                                                      const int* __restrict__ flag,
                                                      const float* __restrict__ feat,
                                                      float* __restrict__ msg,
                                                      float* __restrict__ deg) {
    const long long g = (long long)blockIdx.x * blockDim.x + threadIdx.x;
    const long long e = g >> 5;
    const int lane = (int)(g & 31);
    if (e >= NE) return;
    const int f = *flag;
    const size_t si = f ? (size_t)(2 * e)                   : (size_t)e;
    const size_t di = f ? (size_t)(2 * ((long long)NE + e)) : (size_t)((long long)NE + e);
    const unsigned src = ei[si];
    const unsigned dst = ei[di];
    float4 v = *(const float4*)(feat + (size_t)src * HID + lane * 4);
    float* m = msg + (size_t)dst * HID + lane * 4;
    atomicAdd(m + 0, fmaxf(v.x, 0.f));
    atomicAdd(m + 1, fmaxf(v.y, 0.f));
    atomicAdd(m + 2, fmaxf(v.z, 0.f));
    atomicAdd(m + 3, fmaxf(v.w, 0.f));
    if (lane == 0) atomicAdd(deg + dst, 1.0f);
}

__global__ __launch_bounds__(256) void divide_kernel(float* __restrict__ agg,
                                                     const float* __restrict__ deg) {
    const int i = blockIdx.x * 256 + threadIdx.x;   // one float4 per thread
    if (i >= NN * (HID / 4)) return;
    const int n = i >> 5;
    const float d = fmaxf(deg[n], 1.0f);
    float4 v = ((float4*)agg)[i];
    v.x /= d; v.y /= d; v.z /= d; v.w /= d;
    ((float4*)agg)[i] = v;
}

// ---------------------------------------------------------------------------
// Combine: out_feat = agg @ Wl + bl + relu(feat) @ Wr ; out = 10*rownorm @ WnHat
// agg is read from (and out_feat written to) the ofeat region.
// ---------------------------------------------------------------------------
#define NT 16
__global__ __launch_bounds__(256) void combine_kernel(const float* __restrict__ Wl,
                                                      const float* __restrict__ bl,
                                                      const float* __restrict__ Wr,
                                                      const float* __restrict__ WnHat,
                                                      const float* __restrict__ feat,
                                                      float* __restrict__ out,
                                                      float* __restrict__ ofeat) {
    __shared__ float sWl[HID][HID];
    __shared__ float sWr[HID][HID];
    __shared__ float sWn[HID][NC];
    __shared__ float sBl[HID];
    __shared__ float sA[NT][HID];
    __shared__ float sH[NT][HID];
    __shared__ float sScale[NT];

    const int t = threadIdx.x;

    for (int i = t; i < HID * HID / 4; i += 256) {
        ((float4*)sWl)[i] = ((const float4*)Wl)[i];
        ((float4*)sWr)[i] = ((const float4*)Wr)[i];
    }
    for (int i = t; i < HID * NC; i += 256) ((float*)sWn)[i] = WnHat[i];
    if (t < HID) sBl[t] = bl[t];

    const int cg = t & 31;
    const int ng = t >> 5;
    const int c0 = cg * 4;
    const int n0 = ng * 2, n1 = ng * 2 + 1;
    const int nchunks = NN / NT;

    for (int ch = blockIdx.x; ch < nchunks; ch += gridDim.x) {
        const int base = ch * NT;
        __syncthreads();

        for (int i = t; i < NT * (HID / 4); i += 256) {
            const int n = i >> 5;
            const int k4 = (i & 31) * 4;
            const int node = base + n;
            *(float4*)&sA[n][k4] = *(const float4*)(ofeat + (size_t)node * HID + k4);
            float4 fv = *(const float4*)(feat + (size_t)node * HID + k4);
            sH[n][k4 + 0] = fmaxf(fv.x, 0.f); sH[n][k4 + 1] = fmaxf(fv.y, 0.f);
            sH[n][k4 + 2] = fmaxf(fv.z, 0.f); sH[n][k4 + 3] = fmaxf(fv.w, 0.f);
        }
        __syncthreads();

        float4 acc0, acc1;
        acc0.x = sBl[c0]; acc0.y = sBl[c0 + 1]; acc0.z = sBl[c0 + 2]; acc0.w = sBl[c0 + 3];
        acc1 = acc0;
#pragma unroll 8
        for (int k = 0; k < HID; ++k) {
            const float4 wl = *(const float4*)&sWl[k][c0];
            const float4 wr = *(const float4*)&sWr[k][c0];
            const float a0 = sA[n0][k], a1 = sA[n1][k];
            const float h0 = sH[n0][k], h1 = sH[n1][k];
            acc0.x = fmaf(a0, wl.x, acc0.x); acc0.y = fmaf(a0, wl.y, acc0.y);
            acc0.z = fmaf(a0, wl.z, acc0.z); acc0.w = fmaf(a0, wl.w, acc0.w);
            acc0.x = fmaf(h0, wr.x, acc0.x); acc0.y = fmaf(h0, wr.y, acc0.y);
            acc0.z = fmaf(h0, wr.z, acc0.z); acc0.w = fmaf(h0, wr.w, acc0.w);
            acc1.x = fmaf(a1, wl.x, acc1.x); acc1.y = fmaf(a1, wl.y, acc1.y);
            acc1.z = fmaf(a1, wl.z, acc1.z); acc1.w = fmaf(a1, wl.w, acc1.w);
            acc1.x = fmaf(h1, wr.x, acc1.x); acc1.y = fmaf(h1, wr.y, acc1.y);
            acc1.z = fmaf(h1, wr.z, acc1.z); acc1.w = fmaf(h1, wr.w, acc1.w);
        }
        __syncthreads();

        *(float4*)&sA[n0][c0] = acc0;
        *(float4*)&sA[n1][c0] = acc1;
        *(float4*)(ofeat + (size_t)(base + n0) * HID + c0) = acc0;
        *(float4*)(ofeat + (size_t)(base + n1) * HID + c0) = acc1;
        __syncthreads();

        if (t < NT) {
            float s = 0.f;
            for (int k = 0; k < HID; ++k) { const float v = sA[t][k]; s = fmaf(v, v, s); }
            sScale[t] = 10.f / fmaxf(sqrtf(s), 1e-12f);
        }
        __syncthreads();

        for (int i = t; i < NT * NC; i += 256) {
            const int n = i / NC;
            const int c = i % NC;
            float s = 0.f;
            for (int k = 0; k < HID; ++k) s = fmaf(sA[n][k], sWn[k][c], s);
            out[(size_t)(base + n) * NC + c] = sScale[n] * s;
        }
    }
}

// ---------------------------------------------------------------------------
extern "C" void kernel_launch(void* const* d_in, const int* in_sizes, int n_in,
                              void* d_out, int out_size, void* d_ws, size_t ws_size,
                              hipStream_t stream) {
    const float*    x  = (const float*)d_in[0];
    const unsigned* ei = (const unsigned*)d_in[1];
    const float*    W1 = (const float*)d_in[2];
    const float*    b1 = (const float*)d_in[3];
    const float*    Wl = (const float*)d_in[4];
    const float*    bl = (const float*)d_in[5];
    const float*    Wr = (const float*)d_in[6];
    const float*    Wn = (const float*)d_in[7];

    float* out   = (float*)d_out;
    float* feat  = out + FEAT_OFF;
    float* ofeat = out + OFEAT_OFF;   // agg buffer, then out_feat

    char* ws = (char*)d_ws;
    int*   flag   = (int*)(ws + WS_FLAG);
    float* WnHat  = (float*)(ws + WS_WNHAT);
    int*   cnt    = (int*)(ws + WS_CNT);
    int*   rs     = (int*)(ws + WS_ROWS);
    int*   cursor = (int*)(ws + WS_CURSOR);
    int*   bsum   = (int*)(ws + WS_BSUM);
    int*   csr    = (int*)(ws + WS_CSR);

    detect_idx_kernel<<<1, 64, 0, stream>>>(ei, flag);
    wn_norm_kernel<<<1, 32, 0, stream>>>(Wn, WnHat);

    gemm1_kernel<<<(NN + 63) / 64, 256, 0, stream>>>(x, W1, b1, feat);

    if (ws_size >= WS_NEEDED) {
        // CSR pull path
        hipMemsetAsync(cnt, 0, (size_t)NN * sizeof(int), stream);
        hist_kernel<<<(NE + 255) / 256, 256, 0, stream>>>(ei, flag, cnt);
        scan1_kernel<<<NB_SCAN, 1024, 0, stream>>>(cnt, rs, bsum);
        scan2_kernel<<<1, 64, 0, stream>>>(bsum);
        scan3_kernel<<<NB_SCAN, 1024, 0, stream>>>(rs, cursor, bsum);
        fill_kernel<<<(NE + 255) / 256, 256, 0, stream>>>(ei, flag, cursor, csr);
        gather_kernel<<<2048, 256, 0, stream>>>(rs, csr, feat, ofeat);
    } else {
        // Fallback: atomic scatter
        float* deg = (float*)(ws + WS_CNT);
        hipMemsetAsync(ofeat, 0, (size_t)NN * HID * sizeof(float), stream);
        hipMemsetAsync(deg, 0, (size_t)NN * sizeof(float), stream);
        scatter_kernel<<<(int)(((long long)NE * 32) / 256), 256, 0, stream>>>(ei, flag, feat, ofeat, deg);
        divide_kernel<<<(NN * (HID / 4) + 255) / 256, 256, 0, stream>>>(ofeat, deg);
    }

    combine_kernel<<<512, 256, 0, stream>>>(Wl, bl, Wr, WnHat, feat, out, ofeat);
}

// Round 3
// 1141.354 us; speedup vs baseline: 5.7784x; 1.4465x over previous
//
#include <hip/hip_runtime.h>
#include <math.h>

#define NN 100000
#define NE 3200000
#define XD 2000
#define HID 128
#define NC 20

#define FEAT_OFF  ((size_t)NN * NC)                    // 2,000,000
#define OFEAT_OFF (FEAT_OFF + (size_t)NN * HID)        // 14,800,000

// ws layout (bytes)
#define WS_FLAG    0
#define WS_WNHAT   256
#define WS_CNT     16384                // int[NN]  (float deg in fallback)
#define WS_ROWS    417792               // int[NN+1]  (BT in fallback)
#define WS_CURSOR  819200               // int[NN]
#define WS_BSUM    1220608              // int[128]
#define WS_CSR     1245184              // int[NE]   (BT lives here pre-fill)
#define WS_NEEDED  (WS_CSR + (size_t)NE * 4 + 1024)

#define NB_SCAN 98                      // ceil(NN/1024)
#define KPAD 2016                       // 63 K-steps of 32
#define KSTEPS 63

typedef __attribute__((ext_vector_type(8))) short bf16x8;
typedef __attribute__((ext_vector_type(4))) float f32x4;

__device__ inline unsigned short f2bf(float f) {
    unsigned u = __builtin_bit_cast(unsigned, f);
    unsigned r = (u + 0x7fffu + ((u >> 16) & 1u)) >> 16;
    return (unsigned short)r;
}

// ---------------------------------------------------------------------------
__global__ void detect_idx_kernel(const unsigned* __restrict__ ei, int* __restrict__ flag) {
    if (threadIdx.x == 0) {
        bool hz = true;
        for (int i = 0; i < 16; ++i) hz = hz && (ei[2 * i + 1] == 0u);
        *flag = hz ? 1 : 0;
    }
}

__global__ void wn_norm_kernel(const float* __restrict__ Wn, float* __restrict__ WnHat) {
    int c = threadIdx.x;
    if (c >= NC) return;
    float s = 0.f;
    for (int k = 0; k < HID; ++k) { float w = Wn[k * NC + c]; s = fmaf(w, w, s); }
    float inv = 1.f / fmaxf(sqrtf(s), 1e-12f);
    for (int k = 0; k < HID; ++k) WnHat[k * NC + c] = Wn[k * NC + c] * inv;
}

// ---------------------------------------------------------------------------
// W1 [XD][HID] fp32 -> BT bf16, K-step tiled: BT[(k>>5)*4096 + c*32 + (k&31)]
// ---------------------------------------------------------------------------
__global__ __launch_bounds__(256) void w1conv_kernel(const float* __restrict__ W1,
                                                     unsigned short* __restrict__ BT) {
    const int i = blockIdx.x * 256 + threadIdx.x;   // i = k*128 + c, k < KPAD
    if (i >= KPAD * HID) return;
    const int k = i >> 7;
    const int c = i & 127;
    unsigned short v = 0;
    if (k < XD) v = f2bf(W1[(size_t)k * HID + c]);
    BT[(size_t)(k >> 5) * 4096 + c * 32 + (k & 31)] = v;
}

// ---------------------------------------------------------------------------
// GEMM1 (MFMA bf16): feat = x @ W1 + b1.  128x128 tile, 4 waves, BK=32.
// LDS tiles stored [row][k] bf16 with row stride 56 shorts (112 B = 7*16B).
// ---------------------------------------------------------------------------
__global__ __launch_bounds__(256) void gemm1_kernel(const float* __restrict__ x,
                                                    const unsigned short* __restrict__ BT,
                                                    const float* __restrict__ b1,
                                                    float* __restrict__ feat) {
    __shared__ unsigned short sA[128][56];
    __shared__ unsigned short sB[128][56];

    const int t = threadIdx.x;
    const int lane = t & 63;
    const int wid = t >> 6;
    const int wr = wid >> 1;            // wave row block (0..1) -> rows wr*64
    const int wc = wid & 1;             // wave col block -> cols wc*64
    const int row0 = blockIdx.x * 128;

    // stagers
    const int srow = t >> 3;            // 0..31
    const int sk   = (t & 7) * 4;       // 0,4,...,28

    // frag read offsets
    const int fr = lane & 15;
    const int fk = (lane >> 4) * 8;     // k-offset within BK

    float bias[4];
#pragma unroll
    for (int j = 0; j < 4; ++j) bias[j] = b1[wc * 64 + j * 16 + fr];

    f32x4 acc[4][4];
#pragma unroll
    for (int i = 0; i < 4; ++i)
#pragma unroll
        for (int j = 0; j < 4; ++j) acc[i][j] = (f32x4)0.f;

    for (int k0 = 0; k0 < KPAD; k0 += 32) {
        // ---- global loads (A fp32, B pre-tiled bf16) ----
        float4 xv[4];
#pragma unroll
        for (int p = 0; p < 4; ++p) {
            const int gr = row0 + srow + p * 32;
            const int gk = k0 + sk;
            float4 v = make_float4(0.f, 0.f, 0.f, 0.f);
            if (gr < NN && gk < XD) v = *(const float4*)(x + (size_t)gr * XD + gk);
            xv[p] = v;
        }
        bf16x8 bv[2];
        {
            const unsigned short* bs = BT + (size_t)(k0 >> 5) * 4096;
#pragma unroll
            for (int p = 0; p < 2; ++p)
                bv[p] = *(const bf16x8*)(bs + (size_t)(t + p * 256) * 8);
        }

        __syncthreads();   // previous iteration's LDS reads complete

        // ---- LDS writes ----
#pragma unroll
        for (int p = 0; p < 4; ++p) {
            const unsigned short b0 = f2bf(xv[p].x), b1s = f2bf(xv[p].y);
            const unsigned short b2 = f2bf(xv[p].z), b3 = f2bf(xv[p].w);
            uint2 w;
            w.x = (unsigned)b0 | ((unsigned)b1s << 16);
            w.y = (unsigned)b2 | ((unsigned)b3 << 16);
            *(uint2*)&sA[srow + p * 32][sk] = w;
        }
#pragma unroll
        for (int p = 0; p < 2; ++p) {
            const int i = t + p * 256;        // col = i>>2, kq = (i&3)*8
            *(bf16x8*)&sB[i >> 2][(i & 3) * 8] = bv[p];
        }

        __syncthreads();   // tile ready

        // ---- fragments + MFMA ----
        bf16x8 af[4], bfr[4];
#pragma unroll
        for (int i = 0; i < 4; ++i)
            af[i] = *(const bf16x8*)&sA[wr * 64 + i * 16 + fr][fk];
#pragma unroll
        for (int j = 0; j < 4; ++j)
            bfr[j] = *(const bf16x8*)&sB[wc * 64 + j * 16 + fr][fk];

#pragma unroll
        for (int i = 0; i < 4; ++i)
#pragma unroll
            for (int j = 0; j < 4; ++j)
                acc[i][j] = __builtin_amdgcn_mfma_f32_16x16x32_bf16(af[i], bfr[j], acc[i][j], 0, 0, 0);
    }

    // ---- epilogue: C[row][col], row=(lane>>4)*4+r, col=lane&15 within frag ----
    const int rb = row0 + wr * 64 + (lane >> 4) * 4;
    const int cb = wc * 64 + fr;
#pragma unroll
    for (int i = 0; i < 4; ++i) {
#pragma unroll
        for (int r = 0; r < 4; ++r) {
            const int row = rb + i * 16 + r;
            if (row < NN) {
#pragma unroll
                for (int j = 0; j < 4; ++j)
                    feat[(size_t)row * HID + cb + j * 16] = acc[i][j][r] + bias[j];
            }
        }
    }
}

// ---------------------------------------------------------------------------
// CSR build: histogram, 3-step scan, fill
// ---------------------------------------------------------------------------
__global__ __launch_bounds__(256) void hist_kernel(const unsigned* __restrict__ ei,
                                                   const int* __restrict__ flag,
                                                   int* __restrict__ cnt) {
    const long long e = (long long)blockIdx.x * blockDim.x + threadIdx.x;
    if (e >= NE) return;
    const int f = *flag;
    const size_t di = f ? (size_t)(2 * ((long long)NE + e)) : (size_t)((long long)NE + e);
    atomicAdd(&cnt[ei[di]], 1);
}

__global__ __launch_bounds__(1024) void scan1_kernel(const int* __restrict__ cnt,
                                                     int* __restrict__ rs,
                                                     int* __restrict__ bsum) {
    __shared__ int sd[1024];
    const int t = threadIdx.x;
    const int i = blockIdx.x * 1024 + t;
    const int v = (i < NN) ? cnt[i] : 0;
    sd[t] = v;
    __syncthreads();
    for (int off = 1; off < 1024; off <<= 1) {
        const int u = (t >= off) ? sd[t - off] : 0;
        __syncthreads();
        sd[t] += u;
        __syncthreads();
    }
    if (i < NN) rs[i] = sd[t] - v;
    if (t == 1023) bsum[blockIdx.x] = sd[1023];
}

__global__ void scan2_kernel(int* __restrict__ bsum) {
    if (threadIdx.x == 0) {
        int run = 0;
        for (int b = 0; b < NB_SCAN; ++b) { const int x = bsum[b]; bsum[b] = run; run += x; }
    }
}

__global__ __launch_bounds__(1024) void scan3_kernel(int* __restrict__ rs,
                                                     int* __restrict__ cursor,
                                                     const int* __restrict__ bsum) {
    const int i = blockIdx.x * 1024 + threadIdx.x;
    if (i < NN) {
        const int v = rs[i] + bsum[i >> 10];
        rs[i] = v;
        cursor[i] = v;
    }
    if (i == 0) rs[NN] = NE;
}

__global__ __launch_bounds__(256) void fill_kernel(const unsigned* __restrict__ ei,
                                                   const int* __restrict__ flag,
                                                   int* __restrict__ cursor,
                                                   int* __restrict__ csr) {
    const long long e = (long long)blockIdx.x * blockDim.x + threadIdx.x;
    if (e >= NE) return;
    const int f = *flag;
    const size_t si = f ? (size_t)(2 * e)                    : (size_t)e;
    const size_t di = f ? (size_t)(2 * ((long long)NE + e))  : (size_t)((long long)NE + e);
    const unsigned src = ei[si];
    const unsigned dst = ei[di];
    const int pos = atomicAdd(&cursor[dst], 1);
    csr[pos] = (int)src;
}

// ---------------------------------------------------------------------------
// Gather (pull): agg[n] = mean_{j in N(n)} relu(feat[src_j]).  One wave/node.
// ---------------------------------------------------------------------------
__global__ __launch_bounds__(256) void gather_kernel(const int* __restrict__ rs,
                                                     const int* __restrict__ csr,
                                                     const float* __restrict__ feat,
                                                     float* __restrict__ agg) {
    const int lane = threadIdx.x & 63;
    const int gw = (blockIdx.x * 256 + threadIdx.x) >> 6;
    const int nw = gridDim.x * 4;
    const int o = lane * 2;

    for (int n = gw; n < NN; n += nw) {
        const int s = rs[n];
        const int e2 = rs[n + 1];
        float ax = 0.f, ay = 0.f;
        int j = s;
        for (; j + 4 <= e2; j += 4) {
            const int s0 = csr[j], s1 = csr[j + 1], s2 = csr[j + 2], s3 = csr[j + 3];
            const float2 v0 = *(const float2*)(feat + (size_t)s0 * HID + o);
            const float2 v1 = *(const float2*)(feat + (size_t)s1 * HID + o);
            const float2 v2 = *(const float2*)(feat + (size_t)s2 * HID + o);
            const float2 v3 = *(const float2*)(feat + (size_t)s3 * HID + o);
            ax += fmaxf(v0.x, 0.f) + fmaxf(v1.x, 0.f) + fmaxf(v2.x, 0.f) + fmaxf(v3.x, 0.f);
            ay += fmaxf(v0.y, 0.f) + fmaxf(v1.y, 0.f) + fmaxf(v2.y, 0.f) + fmaxf(v3.y, 0.f);
        }
        for (; j < e2; ++j) {
            const float2 v = *(const float2*)(feat + (size_t)csr[j] * HID + o);
            ax += fmaxf(v.x, 0.f);
            ay += fmaxf(v.y, 0.f);
        }
        const float d = fmaxf((float)(e2 - s), 1.f);
        *(float2*)(agg + (size_t)n * HID + o) = make_float2(ax / d, ay / d);
    }
}

// ---------------------------------------------------------------------------
// Fallback scatter path (used only if ws too small for CSR)
// ---------------------------------------------------------------------------
__global__ __launch_bounds__(256) void scatter_kernel(const unsigned* __restrict__ ei,
                                                      const int* __restrict__ flag,
                                                      const float* __restrict__ feat,
                                                      float* __restrict__ msg,
                                                      float* __restrict__ deg) {
    const long long g = (long long)blockIdx.x * blockDim.x + threadIdx.x;
    const long long e = g >> 5;
    const int lane = (int)(g & 31);
    if (e >= NE) return;
    const int f = *flag;
    const size_t si = f ? (size_t)(2 * e)                   : (size_t)e;
    const size_t di = f ? (size_t)(2 * ((long long)NE + e)) : (size_t)((long long)NE + e);
    const unsigned src = ei[si];
    const unsigned dst = ei[di];
    float4 v = *(const float4*)(feat + (size_t)src * HID + lane * 4);
    float* m = msg + (size_t)dst * HID + lane * 4;
    atomicAdd(m + 0, fmaxf(v.x, 0.f));
    atomicAdd(m + 1, fmaxf(v.y, 0.f));
    atomicAdd(m + 2, fmaxf(v.z, 0.f));
    atomicAdd(m + 3, fmaxf(v.w, 0.f));
    if (lane == 0) atomicAdd(deg + dst, 1.0f);
}

__global__ __launch_bounds__(256) void divide_kernel(float* __restrict__ agg,
                                                     const float* __restrict__ deg) {
    const int i = blockIdx.x * 256 + threadIdx.x;
    if (i >= NN * (HID / 4)) return;
    const int n = i >> 5;
    const float d = fmaxf(deg[n], 1.0f);
    float4 v = ((float4*)agg)[i];
    v.x /= d; v.y /= d; v.z /= d; v.w /= d;
    ((float4*)agg)[i] = v;
}

// ---------------------------------------------------------------------------
// Combine: out_feat = agg @ Wl + bl + relu(feat) @ Wr ; out = 10*rownorm @ WnHat
// ---------------------------------------------------------------------------
#define NT 16
__global__ __launch_bounds__(256) void combine_kernel(const float* __restrict__ Wl,
                                                      const float* __restrict__ bl,
                                                      const float* __restrict__ Wr,
                                                      const float* __restrict__ WnHat,
                                                      const float* __restrict__ feat,
                                                      float* __restrict__ out,
                                                      float* __restrict__ ofeat) {
    __shared__ float sWl[HID][HID];
    __shared__ float sWr[HID][HID];
    __shared__ float sWn[HID][NC];
    __shared__ float sBl[HID];
    __shared__ float sA[NT][HID];
    __shared__ float sH[NT][HID];
    __shared__ float sScale[NT];

    const int t = threadIdx.x;

    for (int i = t; i < HID * HID / 4; i += 256) {
        ((float4*)sWl)[i] = ((const float4*)Wl)[i];
        ((float4*)sWr)[i] = ((const float4*)Wr)[i];
    }
    for (int i = t; i < HID * NC; i += 256) ((float*)sWn)[i] = WnHat[i];
    if (t < HID) sBl[t] = bl[t];

    const int cg = t & 31;
    const int ng = t >> 5;
    const int c0 = cg * 4;
    const int n0 = ng * 2, n1 = ng * 2 + 1;
    const int nchunks = NN / NT;

    for (int ch = blockIdx.x; ch < nchunks; ch += gridDim.x) {
        const int base = ch * NT;
        __syncthreads();

        for (int i = t; i < NT * (HID / 4); i += 256) {
            const int n = i >> 5;
            const int k4 = (i & 31) * 4;
            const int node = base + n;
            *(float4*)&sA[n][k4] = *(const float4*)(ofeat + (size_t)node * HID + k4);
            float4 fv = *(const float4*)(feat + (size_t)node * HID + k4);
            sH[n][k4 + 0] = fmaxf(fv.x, 0.f); sH[n][k4 + 1] = fmaxf(fv.y, 0.f);
            sH[n][k4 + 2] = fmaxf(fv.z, 0.f); sH[n][k4 + 3] = fmaxf(fv.w, 0.f);
        }
        __syncthreads();

        float4 acc0, acc1;
        acc0.x = sBl[c0]; acc0.y = sBl[c0 + 1]; acc0.z = sBl[c0 + 2]; acc0.w = sBl[c0 + 3];
        acc1 = acc0;
#pragma unroll 8
        for (int k = 0; k < HID; ++k) {
            const float4 wl = *(const float4*)&sWl[k][c0];
            const float4 wr = *(const float4*)&sWr[k][c0];
            const float a0 = sA[n0][k], a1 = sA[n1][k];
            const float h0 = sH[n0][k], h1 = sH[n1][k];
            acc0.x = fmaf(a0, wl.x, acc0.x); acc0.y = fmaf(a0, wl.y, acc0.y);
            acc0.z = fmaf(a0, wl.z, acc0.z); acc0.w = fmaf(a0, wl.w, acc0.w);
            acc0.x = fmaf(h0, wr.x, acc0.x); acc0.y = fmaf(h0, wr.y, acc0.y);
            acc0.z = fmaf(h0, wr.z, acc0.z); acc0.w = fmaf(h0, wr.w, acc0.w);
            acc1.x = fmaf(a1, wl.x, acc1.x); acc1.y = fmaf(a1, wl.y, acc1.y);
            acc1.z = fmaf(a1, wl.z, acc1.z); acc1.w = fmaf(a1, wl.w, acc1.w);
            acc1.x = fmaf(h1, wr.x, acc1.x); acc1.y = fmaf(h1, wr.y, acc1.y);
            acc1.z = fmaf(h1, wr.z, acc1.z); acc1.w = fmaf(h1, wr.w, acc1.w);
        }
        __syncthreads();

        *(float4*)&sA[n0][c0] = acc0;
        *(float4*)&sA[n1][c0] = acc1;
        *(float4*)(ofeat + (size_t)(base + n0) * HID + c0) = acc0;
        *(float4*)(ofeat + (size_t)(base + n1) * HID + c0) = acc1;
        __syncthreads();

        if (t < NT) {
            float s = 0.f;
            for (int k = 0; k < HID; ++k) { const float v = sA[t][k]; s = fmaf(v, v, s); }
            sScale[t] = 10.f / fmaxf(sqrtf(s), 1e-12f);
        }
        __syncthreads();

        for (int i = t; i < NT * NC; i += 256) {
            const int n = i / NC;
            const int c = i % NC;
            float s = 0.f;
            for (int k = 0; k < HID; ++k) s = fmaf(sA[n][k], sWn[k][c], s);
            out[(size_t)(base + n) * NC + c] = sScale[n] * s;
        }
    }
}

// ---------------------------------------------------------------------------
extern "C" void kernel_launch(void* const* d_in, const int* in_sizes, int n_in,
                              void* d_out, int out_size, void* d_ws, size_t ws_size,
                              hipStream_t stream) {
    const float*    x  = (const float*)d_in[0];
    const unsigned* ei = (const unsigned*)d_in[1];
    const float*    W1 = (const float*)d_in[2];
    const float*    b1 = (const float*)d_in[3];
    const float*    Wl = (const float*)d_in[4];
    const float*    bl = (const float*)d_in[5];
    const float*    Wr = (const float*)d_in[6];
    const float*    Wn = (const float*)d_in[7];

    float* out   = (float*)d_out;
    float* feat  = out + FEAT_OFF;
    float* ofeat = out + OFEAT_OFF;

    char* ws = (char*)d_ws;
    int*   flag   = (int*)(ws + WS_FLAG);
    float* WnHat  = (float*)(ws + WS_WNHAT);
    int*   cnt    = (int*)(ws + WS_CNT);
    int*   rs     = (int*)(ws + WS_ROWS);
    int*   cursor = (int*)(ws + WS_CURSOR);
    int*   bsum   = (int*)(ws + WS_BSUM);
    int*   csr    = (int*)(ws + WS_CSR);

    const bool big_ws = (ws_size >= WS_NEEDED);
    // BT (bf16 W1 image, 516 KB): lives in the CSR region (dead until fill_kernel)
    // on the main path, or in the rs/cursor region on the fallback path.
    unsigned short* BT = (unsigned short*)(big_ws ? (void*)csr : (void*)(ws + WS_ROWS));

    detect_idx_kernel<<<1, 64, 0, stream>>>(ei, flag);
    wn_norm_kernel<<<1, 32, 0, stream>>>(Wn, WnHat);
    w1conv_kernel<<<(KPAD * HID + 255) / 256, 256, 0, stream>>>(W1, BT);

    gemm1_kernel<<<(NN + 127) / 128, 256, 0, stream>>>(x, BT, b1, feat);

    if (big_ws) {
        hipMemsetAsync(cnt, 0, (size_t)NN * sizeof(int), stream);
        hist_kernel<<<(NE + 255) / 256, 256, 0, stream>>>(ei, flag, cnt);
        scan1_kernel<<<NB_SCAN, 1024, 0, stream>>>(cnt, rs, bsum);
        scan2_kernel<<<1, 64, 0, stream>>>(bsum);
        scan3_kernel<<<NB_SCAN, 1024, 0, stream>>>(rs, cursor, bsum);
        fill_kernel<<<(NE + 255) / 256, 256, 0, stream>>>(ei, flag, cursor, csr);
        gather_kernel<<<2048, 256, 0, stream>>>(rs, csr, feat, ofeat);
    } else {
        float* deg = (float*)(ws + WS_CNT);
        hipMemsetAsync(ofeat, 0, (size_t)NN * HID * sizeof(float), stream);
        hipMemsetAsync(deg, 0, (size_t)NN * sizeof(float), stream);
        scatter_kernel<<<(int)(((long long)NE * 32) / 256), 256, 0, stream>>>(ei, flag, feat, ofeat, deg);
        divide_kernel<<<(NN * (HID / 4) + 255) / 256, 256, 0, stream>>>(ofeat, deg);
    }

    combine_kernel<<<512, 256, 0, stream>>>(Wl, bl, Wr, WnHat, feat, out, ofeat);
}

// Round 4
// 998.291 us; speedup vs baseline: 6.6064x; 1.1433x over previous
//
#include <hip/hip_runtime.h>
#include <math.h>

#define NN 100000
#define NE 3200000
#define XD 2000
#define HID 128
#define NC 20

#define FEAT_OFF  ((size_t)NN * NC)                    // 2,000,000
#define OFEAT_OFF (FEAT_OFF + (size_t)NN * HID)        // 14,800,000

// ws layout (bytes)
#define WS_FLAG    0
#define WS_WNHAT   256
#define WS_CNT     16384                // int[NN]  (float deg in fallback)
#define WS_ROWS    417792               // int[NN+1]  (BT in fallback)
#define WS_CURSOR  819200               // int[NN]
#define WS_BSUM    1220608              // int[128]
#define WS_CSR     1245184              // int[NE]   (BT lives here pre-fill)
#define WS_HB      14045184            // bf16[NN*HID] relu(feat)
#define WS_NEEDED  (WS_HB + (size_t)NN * HID * 2 + 1024)

#define NB_SCAN 98                      // ceil(NN/1024)
#define KPAD 2016                       // 63 K-steps of 32

typedef __attribute__((ext_vector_type(8))) short bf16x8;
typedef __attribute__((ext_vector_type(4))) float f32x4;

__device__ inline unsigned short f2bf(float f) {
    unsigned u = __builtin_bit_cast(unsigned, f);
    unsigned r = (u + 0x7fffu + ((u >> 16) & 1u)) >> 16;
    return (unsigned short)r;
}
__device__ inline float bf2f(unsigned short h) {
    return __builtin_bit_cast(float, ((unsigned)h) << 16);
}

// ---------------------------------------------------------------------------
__global__ void detect_idx_kernel(const unsigned* __restrict__ ei, int* __restrict__ flag) {
    if (threadIdx.x == 0) {
        bool hz = true;
        for (int i = 0; i < 16; ++i) hz = hz && (ei[2 * i + 1] == 0u);
        *flag = hz ? 1 : 0;
    }
}

__global__ void wn_norm_kernel(const float* __restrict__ Wn, float* __restrict__ WnHat) {
    int c = threadIdx.x;
    if (c >= NC) return;
    float s = 0.f;
    for (int k = 0; k < HID; ++k) { float w = Wn[k * NC + c]; s = fmaf(w, w, s); }
    float inv = 1.f / fmaxf(sqrtf(s), 1e-12f);
    for (int k = 0; k < HID; ++k) WnHat[k * NC + c] = Wn[k * NC + c] * inv;
}

// ---------------------------------------------------------------------------
// W1 [XD][HID] fp32 -> BT bf16, K-step tiled: BT[(k>>5)*4096 + c*32 + (k&31)]
// ---------------------------------------------------------------------------
__global__ __launch_bounds__(256) void w1conv_kernel(const float* __restrict__ W1,
                                                     unsigned short* __restrict__ BT) {
    const int i = blockIdx.x * 256 + threadIdx.x;
    if (i >= KPAD * HID) return;
    const int k = i >> 7;
    const int c = i & 127;
    unsigned short v = 0;
    if (k < XD) v = f2bf(W1[(size_t)k * HID + c]);
    BT[(size_t)(k >> 5) * 4096 + c * 32 + (k & 31)] = v;
}

// ---------------------------------------------------------------------------
// GEMM1 (MFMA bf16): feat = x @ W1 + b1; also hb = bf16(relu(feat)) if hb!=0.
// ---------------------------------------------------------------------------
__global__ __launch_bounds__(256) void gemm1_kernel(const float* __restrict__ x,
                                                    const unsigned short* __restrict__ BT,
                                                    const float* __restrict__ b1,
                                                    float* __restrict__ feat,
                                                    unsigned short* __restrict__ hb) {
    __shared__ unsigned short sA[128][56];
    __shared__ unsigned short sB[128][56];

    const int t = threadIdx.x;
    const int lane = t & 63;
    const int wid = t >> 6;
    const int wr = wid >> 1;
    const int wc = wid & 1;
    const int row0 = blockIdx.x * 128;

    const int srow = t >> 3;
    const int sk   = (t & 7) * 4;

    const int fr = lane & 15;
    const int fk = (lane >> 4) * 8;

    float bias[4];
#pragma unroll
    for (int j = 0; j < 4; ++j) bias[j] = b1[wc * 64 + j * 16 + fr];

    f32x4 acc[4][4];
#pragma unroll
    for (int i = 0; i < 4; ++i)
#pragma unroll
        for (int j = 0; j < 4; ++j) acc[i][j] = (f32x4)0.f;

    for (int k0 = 0; k0 < KPAD; k0 += 32) {
        float4 xv[4];
#pragma unroll
        for (int p = 0; p < 4; ++p) {
            const int gr = row0 + srow + p * 32;
            const int gk = k0 + sk;
            float4 v = make_float4(0.f, 0.f, 0.f, 0.f);
            if (gr < NN && gk < XD) v = *(const float4*)(x + (size_t)gr * XD + gk);
            xv[p] = v;
        }
        bf16x8 bv[2];
        {
            const unsigned short* bs = BT + (size_t)(k0 >> 5) * 4096;
#pragma unroll
            for (int p = 0; p < 2; ++p)
                bv[p] = *(const bf16x8*)(bs + (size_t)(t + p * 256) * 8);
        }

        __syncthreads();

#pragma unroll
        for (int p = 0; p < 4; ++p) {
            const unsigned short b0 = f2bf(xv[p].x), b1s = f2bf(xv[p].y);
            const unsigned short b2 = f2bf(xv[p].z), b3 = f2bf(xv[p].w);
            uint2 w;
            w.x = (unsigned)b0 | ((unsigned)b1s << 16);
            w.y = (unsigned)b2 | ((unsigned)b3 << 16);
            *(uint2*)&sA[srow + p * 32][sk] = w;
        }
#pragma unroll
        for (int p = 0; p < 2; ++p) {
            const int i = t + p * 256;
            *(bf16x8*)&sB[i >> 2][(i & 3) * 8] = bv[p];
        }

        __syncthreads();

        bf16x8 af[4], bfr[4];
#pragma unroll
        for (int i = 0; i < 4; ++i)
            af[i] = *(const bf16x8*)&sA[wr * 64 + i * 16 + fr][fk];
#pragma unroll
        for (int j = 0; j < 4; ++j)
            bfr[j] = *(const bf16x8*)&sB[wc * 64 + j * 16 + fr][fk];

#pragma unroll
        for (int i = 0; i < 4; ++i)
#pragma unroll
            for (int j = 0; j < 4; ++j)
                acc[i][j] = __builtin_amdgcn_mfma_f32_16x16x32_bf16(af[i], bfr[j], acc[i][j], 0, 0, 0);
    }

    const int rb = row0 + wr * 64 + (lane >> 4) * 4;
    const int cb = wc * 64 + fr;
#pragma unroll
    for (int i = 0; i < 4; ++i) {
#pragma unroll
        for (int r = 0; r < 4; ++r) {
            const int row = rb + i * 16 + r;
            if (row < NN) {
#pragma unroll
                for (int j = 0; j < 4; ++j) {
                    const float v = acc[i][j][r] + bias[j];
                    feat[(size_t)row * HID + cb + j * 16] = v;
                    if (hb) hb[(size_t)row * HID + cb + j * 16] = f2bf(fmaxf(v, 0.f));
                }
            }
        }
    }
}

// ---------------------------------------------------------------------------
// CSR build: histogram, 3-step scan, fill
// ---------------------------------------------------------------------------
__global__ __launch_bounds__(256) void hist_kernel(const unsigned* __restrict__ ei,
                                                   const int* __restrict__ flag,
                                                   int* __restrict__ cnt) {
    const long long e = (long long)blockIdx.x * blockDim.x + threadIdx.x;
    if (e >= NE) return;
    const int f = *flag;
    const size_t di = f ? (size_t)(2 * ((long long)NE + e)) : (size_t)((long long)NE + e);
    atomicAdd(&cnt[ei[di]], 1);
}

__global__ __launch_bounds__(1024) void scan1_kernel(const int* __restrict__ cnt,
                                                     int* __restrict__ rs,
                                                     int* __restrict__ bsum) {
    __shared__ int sd[1024];
    const int t = threadIdx.x;
    const int i = blockIdx.x * 1024 + t;
    const int v = (i < NN) ? cnt[i] : 0;
    sd[t] = v;
    __syncthreads();
    for (int off = 1; off < 1024; off <<= 1) {
        const int u = (t >= off) ? sd[t - off] : 0;
        __syncthreads();
        sd[t] += u;
        __syncthreads();
    }
    if (i < NN) rs[i] = sd[t] - v;
    if (t == 1023) bsum[blockIdx.x] = sd[1023];
}

__global__ void scan2_kernel(int* __restrict__ bsum) {
    if (threadIdx.x == 0) {
        int run = 0;
        for (int b = 0; b < NB_SCAN; ++b) { const int x = bsum[b]; bsum[b] = run; run += x; }
    }
}

__global__ __launch_bounds__(1024) void scan3_kernel(int* __restrict__ rs,
                                                     int* __restrict__ cursor,
                                                     const int* __restrict__ bsum) {
    const int i = blockIdx.x * 1024 + threadIdx.x;
    if (i < NN) {
        const int v = rs[i] + bsum[i >> 10];
        rs[i] = v;
        cursor[i] = v;
    }
    if (i == 0) rs[NN] = NE;
}

__global__ __launch_bounds__(256) void fill_kernel(const unsigned* __restrict__ ei,
                                                   const int* __restrict__ flag,
                                                   int* __restrict__ cursor,
                                                   int* __restrict__ csr) {
    const long long e = (long long)blockIdx.x * blockDim.x + threadIdx.x;
    if (e >= NE) return;
    const int f = *flag;
    const size_t si = f ? (size_t)(2 * e)                    : (size_t)e;
    const size_t di = f ? (size_t)(2 * ((long long)NE + e))  : (size_t)((long long)NE + e);
    const unsigned src = ei[si];
    const unsigned dst = ei[di];
    const int pos = atomicAdd(&cursor[dst], 1);
    csr[pos] = (int)src;
}

// ---------------------------------------------------------------------------
// Gather (pull, bf16): agg[n] = mean_{j in N(n)} hb[src_j].  One wave/node.
// ---------------------------------------------------------------------------
__global__ __launch_bounds__(256) void gather_kernel(const int* __restrict__ rs,
                                                     const int* __restrict__ csr,
                                                     const unsigned short* __restrict__ hb,
                                                     float* __restrict__ agg) {
    const int lane = threadIdx.x & 63;
    const int gw = (blockIdx.x * 256 + threadIdx.x) >> 6;
    const int nw = gridDim.x * 4;
    const int o = lane * 2;

    for (int n = gw; n < NN; n += nw) {
        const int s = rs[n];
        const int e2 = rs[n + 1];
        float ax = 0.f, ay = 0.f;
        int j = s;
        for (; j + 4 <= e2; j += 4) {
            const int s0 = csr[j], s1 = csr[j + 1], s2 = csr[j + 2], s3 = csr[j + 3];
            const unsigned u0 = *(const unsigned*)(hb + (size_t)s0 * HID + o);
            const unsigned u1 = *(const unsigned*)(hb + (size_t)s1 * HID + o);
            const unsigned u2 = *(const unsigned*)(hb + (size_t)s2 * HID + o);
            const unsigned u3 = *(const unsigned*)(hb + (size_t)s3 * HID + o);
            ax += __builtin_bit_cast(float, u0 << 16) + __builtin_bit_cast(float, u1 << 16)
                + __builtin_bit_cast(float, u2 << 16) + __builtin_bit_cast(float, u3 << 16);
            ay += __builtin_bit_cast(float, u0 & 0xffff0000u) + __builtin_bit_cast(float, u1 & 0xffff0000u)
                + __builtin_bit_cast(float, u2 & 0xffff0000u) + __builtin_bit_cast(float, u3 & 0xffff0000u);
        }
        for (; j < e2; ++j) {
            const unsigned u = *(const unsigned*)(hb + (size_t)csr[j] * HID + o);
            ax += __builtin_bit_cast(float, u << 16);
            ay += __builtin_bit_cast(float, u & 0xffff0000u);
        }
        const float d = fmaxf((float)(e2 - s), 1.f);
        *(float2*)(agg + (size_t)n * HID + o) = make_float2(ax / d, ay / d);
    }
}

// ---------------------------------------------------------------------------
// Fallback scatter path (tiny ws)
// ---------------------------------------------------------------------------
__global__ __launch_bounds__(256) void scatter_kernel(const unsigned* __restrict__ ei,
                                                      const int* __restrict__ flag,
                                                      const float* __restrict__ feat,
                                                      float* __restrict__ msg,
                                                      float* __restrict__ deg) {
    const long long g = (long long)blockIdx.x * blockDim.x + threadIdx.x;
    const long long e = g >> 5;
    const int lane = (int)(g & 31);
    if (e >= NE) return;
    const int f = *flag;
    const size_t si = f ? (size_t)(2 * e)                   : (size_t)e;
    const size_t di = f ? (size_t)(2 * ((long long)NE + e)) : (size_t)((long long)NE + e);
    const unsigned src = ei[si];
    const unsigned dst = ei[di];
    float4 v = *(const float4*)(feat + (size_t)src * HID + lane * 4);
    float* m = msg + (size_t)dst * HID + lane * 4;
    atomicAdd(m + 0, fmaxf(v.x, 0.f));
    atomicAdd(m + 1, fmaxf(v.y, 0.f));
    atomicAdd(m + 2, fmaxf(v.z, 0.f));
    atomicAdd(m + 3, fmaxf(v.w, 0.f));
    if (lane == 0) atomicAdd(deg + dst, 1.0f);
}

__global__ __launch_bounds__(256) void divide_kernel(float* __restrict__ agg,
                                                     const float* __restrict__ deg) {
    const int i = blockIdx.x * 256 + threadIdx.x;
    if (i >= NN * (HID / 4)) return;
    const int n = i >> 5;
    const float d = fmaxf(deg[n], 1.0f);
    float4 v = ((float4*)agg)[i];
    v.x /= d; v.y /= d; v.z /= d; v.w /= d;
    ((float4*)agg)[i] = v;
}

// ---------------------------------------------------------------------------
// Combine (MFMA, hi/lo split): out_feat = agg @ Wl + bl + relu(feat) @ Wr.
// In-place: agg is read from and out_feat written to the ofeat region.
// B = [Wl;Wr] (K=256) split Bh+Bl in swizzled LDS (128 KB, persistent/block).
// A split in-register. acc = Ah*Bh + Al*Bh + Ah*Bl  (error ~1e-5).
// 64 rows/chunk, 4 waves x (16 rows x 128 cols).
// ---------------------------------------------------------------------------
__global__ __launch_bounds__(256) void combine_kernel(const float* __restrict__ Wl,
                                                      const float* __restrict__ bl,
                                                      const float* __restrict__ Wr,
                                                      const float* __restrict__ feat,
                                                      float* __restrict__ ofeat) {
    __shared__ unsigned short sB[2][128][256];   // [h/l][col][k] swizzled, 128 KB

    const int t = threadIdx.x;
    const int lane = t & 63;
    const int wv = t >> 6;

    // stage split weights (once per block)
    for (int i = t; i < 256 * 128; i += 256) {
        const int k = i >> 7;
        const int c = i & 127;
        const float w = (k < 128) ? Wl[(size_t)k * 128 + c] : Wr[(size_t)(k - 128) * 128 + c];
        const unsigned short h = f2bf(w);
        const unsigned short lo = f2bf(w - bf2f(h));
        const int byte = (c * 512 + k * 2) ^ ((c & 7) << 4);
        *(unsigned short*)((char*)&sB[0][0][0] + byte) = h;
        *(unsigned short*)((char*)&sB[1][0][0] + byte) = lo;
    }
    __syncthreads();

    const int fr = lane & 15;
    const int fk = lane >> 4;          // 0..3
    float blv[8];
#pragma unroll
    for (int j = 0; j < 8; ++j) blv[j] = bl[j * 16 + fr];

    const int nch = (NN + 63) / 64;    // 1563
    for (int ch = blockIdx.x; ch < nch; ch += gridDim.x) {
        const int row = ch * 64 + wv * 16 + fr;
        const int rowc = (row < NN) ? row : (NN - 1);

        // preload all A raw values (8 K-steps x 8 fp32)
        float4 araw[8][2];
#pragma unroll
        for (int s = 0; s < 8; ++s) {
            const int ks = s * 32 + fk * 8;
            const float* src = (s < 4) ? (feat - (size_t)0 + 0, (const float*)0) : (const float*)0;
            (void)src;
            const float* p = (s < 4) ? (ofeat + (size_t)rowc * HID + ks)
                                     : (feat + (size_t)rowc * HID + (ks - 128));
            float4 v0 = *(const float4*)(p);
            float4 v1 = *(const float4*)(p + 4);
            if (s >= 4) {
                v0.x = fmaxf(v0.x, 0.f); v0.y = fmaxf(v0.y, 0.f);
                v0.z = fmaxf(v0.z, 0.f); v0.w = fmaxf(v0.w, 0.f);
                v1.x = fmaxf(v1.x, 0.f); v1.y = fmaxf(v1.y, 0.f);
                v1.z = fmaxf(v1.z, 0.f); v1.w = fmaxf(v1.w, 0.f);
            }
            araw[s][0] = v0; araw[s][1] = v1;
        }

        f32x4 acc[8];
#pragma unroll
        for (int j = 0; j < 8; ++j) { acc[j][0] = blv[j]; acc[j][1] = blv[j]; acc[j][2] = blv[j]; acc[j][3] = blv[j]; }

#pragma unroll
        for (int s = 0; s < 8; ++s) {
            float av[8] = {araw[s][0].x, araw[s][0].y, araw[s][0].z, araw[s][0].w,
                           araw[s][1].x, araw[s][1].y, araw[s][1].z, araw[s][1].w};
            bf16x8 ah, al;
#pragma unroll
            for (int q = 0; q < 8; ++q) {
                const unsigned short h = f2bf(av[q]);
                ah[q] = (short)h;
                al[q] = (short)f2bf(av[q] - bf2f(h));
            }
            const int kb = (s * 32 + fk * 8) * 2;
#pragma unroll
            for (int j = 0; j < 8; ++j) {
                const int col = j * 16 + fr;
                const int byte = (col * 512 + kb) ^ ((col & 7) << 4);
                const bf16x8 bh = *(const bf16x8*)((const char*)&sB[0][0][0] + byte);
                const bf16x8 blo = *(const bf16x8*)((const char*)&sB[1][0][0] + byte);
                acc[j] = __builtin_amdgcn_mfma_f32_16x16x32_bf16(ah, bh, acc[j], 0, 0, 0);
                acc[j] = __builtin_amdgcn_mfma_f32_16x16x32_bf16(al, bh, acc[j], 0, 0, 0);
                acc[j] = __builtin_amdgcn_mfma_f32_16x16x32_bf16(ah, blo, acc[j], 0, 0, 0);
            }
        }

        // store: C layout col=lane&15, row=(lane>>4)*4+r
        const int rb = ch * 64 + wv * 16 + fk * 4;
#pragma unroll
        for (int r = 0; r < 4; ++r) {
            const int rowo = rb + r;
            if (rowo < NN) {
#pragma unroll
                for (int j = 0; j < 8; ++j)
                    ofeat[(size_t)rowo * HID + j * 16 + fr] = acc[j][r];
            }
        }
    }
}

// ---------------------------------------------------------------------------
// Out: out = 10 * rownorm(out_feat) @ WnHat.  32 nodes per tile.
// ---------------------------------------------------------------------------
__global__ __launch_bounds__(256) void out_kernel(const float* __restrict__ ofeat,
                                                  const float* __restrict__ WnHat,
                                                  float* __restrict__ out) {
    __shared__ float sWn[HID][NC];
    __shared__ float sRow[32][HID];
    __shared__ float sPs[32][8];
    __shared__ float sScale[32];

    const int t = threadIdx.x;
    for (int i = t; i < HID * NC; i += 256) ((float*)sWn)[i] = WnHat[i];

    const int ntile = NN / 32;   // 3125 exact
    for (int tb = blockIdx.x; tb < ntile; tb += gridDim.x) {
        const int base = tb * 32;
        __syncthreads();
        for (int i = t; i < 32 * 32; i += 256) {
            const int n = i >> 5;
            const int q = (i & 31) * 4;
            *(float4*)&sRow[n][q] = *(const float4*)(ofeat + (size_t)(base + n) * HID + q);
        }
        __syncthreads();
        {
            const int n = t >> 3, seg = t & 7;
            float s = 0.f;
#pragma unroll
            for (int q = 0; q < 16; ++q) { const float v = sRow[n][seg * 16 + q]; s = fmaf(v, v, s); }
            sPs[n][seg] = s;
        }
        __syncthreads();
        if (t < 32) {
            float s = 0.f;
#pragma unroll
            for (int q = 0; q < 8; ++q) s += sPs[t][q];
            sScale[t] = 10.f / fmaxf(sqrtf(s), 1e-12f);
        }
        __syncthreads();
        for (int i = t; i < 32 * NC; i += 256) {
            const int n = i / NC;
            const int c = i % NC;
            float s = 0.f;
            for (int k = 0; k < HID; ++k) s = fmaf(sRow[n][k], sWn[k][c], s);
            out[(size_t)(base + n) * NC + c] = sScale[n] * s;
        }
    }
}

// ---------------------------------------------------------------------------
extern "C" void kernel_launch(void* const* d_in, const int* in_sizes, int n_in,
                              void* d_out, int out_size, void* d_ws, size_t ws_size,
                              hipStream_t stream) {
    const float*    x  = (const float*)d_in[0];
    const unsigned* ei = (const unsigned*)d_in[1];
    const float*    W1 = (const float*)d_in[2];
    const float*    b1 = (const float*)d_in[3];
    const float*    Wl = (const float*)d_in[4];
    const float*    bl = (const float*)d_in[5];
    const float*    Wr = (const float*)d_in[6];
    const float*    Wn = (const float*)d_in[7];

    float* out   = (float*)d_out;
    float* feat  = out + FEAT_OFF;
    float* ofeat = out + OFEAT_OFF;

    char* ws = (char*)d_ws;
    int*   flag   = (int*)(ws + WS_FLAG);
    float* WnHat  = (float*)(ws + WS_WNHAT);
    int*   cnt    = (int*)(ws + WS_CNT);
    int*   rs     = (int*)(ws + WS_ROWS);
    int*   cursor = (int*)(ws + WS_CURSOR);
    int*   bsum   = (int*)(ws + WS_BSUM);
    int*   csr    = (int*)(ws + WS_CSR);

    const bool big_ws = (ws_size >= WS_NEEDED);
    unsigned short* BT = (unsigned short*)(big_ws ? (void*)csr : (void*)(ws + WS_ROWS));
    unsigned short* hb = big_ws ? (unsigned short*)(ws + WS_HB) : (unsigned short*)0;

    detect_idx_kernel<<<1, 64, 0, stream>>>(ei, flag);
    wn_norm_kernel<<<1, 32, 0, stream>>>(Wn, WnHat);
    w1conv_kernel<<<(KPAD * HID + 255) / 256, 256, 0, stream>>>(W1, BT);

    gemm1_kernel<<<(NN + 127) / 128, 256, 0, stream>>>(x, BT, b1, feat, hb);

    if (big_ws) {
        hipMemsetAsync(cnt, 0, (size_t)NN * sizeof(int), stream);
        hist_kernel<<<(NE + 255) / 256, 256, 0, stream>>>(ei, flag, cnt);
        scan1_kernel<<<NB_SCAN, 1024, 0, stream>>>(cnt, rs, bsum);
        scan2_kernel<<<1, 64, 0, stream>>>(bsum);
        scan3_kernel<<<NB_SCAN, 1024, 0, stream>>>(rs, cursor, bsum);
        fill_kernel<<<(NE + 255) / 256, 256, 0, stream>>>(ei, flag, cursor, csr);
        gather_kernel<<<2048, 256, 0, stream>>>(rs, csr, hb, ofeat);
    } else {
        float* deg = (float*)(ws + WS_CNT);
        hipMemsetAsync(ofeat, 0, (size_t)NN * HID * sizeof(float), stream);
        hipMemsetAsync(deg, 0, (size_t)NN * sizeof(float), stream);
        scatter_kernel<<<(int)(((long long)NE * 32) / 256), 256, 0, stream>>>(ei, flag, feat, ofeat, deg);
        divide_kernel<<<(NN * (HID / 4) + 255) / 256, 256, 0, stream>>>(ofeat, deg);
    }

    combine_kernel<<<256, 256, 0, stream>>>(Wl, bl, Wr, feat, ofeat);
    out_kernel<<<512, 256, 0, stream>>>(ofeat, WnHat, out);
}